// Round 2
// baseline (1141.691 us; speedup 1.0000x reference)
//
#include <hip/hip_runtime.h>
#include <hip/hip_bf16.h>

// B=8192, T=512, IN=1, H=20, OUT=1
#define B_TOTAL 8192
#define T_LEN   512
#define H       20
#define NB      16                // batches per block
#define THREADS (NB * H)          // 320 = 5 waves
#define HP      24                // padded hidden stride: 24*b % 32 banks = {0,24,16,8} disjoint

__device__ __forceinline__ float fast_tanh(float x) {
    // tanh(x) = 1 - 2/(e^{2x}+1)
    float e = __expf(2.0f * x);
    return 1.0f - 2.0f * __builtin_amdgcn_rcpf(e + 1.0f);
}

// dot of 20: h from LDS (float4), w from LDS (float4). 2 accumulators for ILP.
__device__ __forceinline__ float dot20(const float* hp, const float* wp) {
    float a0 = 0.f, a1 = 0.f;
#pragma unroll
    for (int q = 0; q < 5; ++q) {
        float4 h = ((const float4*)hp)[q];
        float4 w = ((const float4*)wp)[q];
        if (q & 1) {
            a1 = fmaf(h.x, w.x, a1); a1 = fmaf(h.y, w.y, a1);
            a1 = fmaf(h.z, w.z, a1); a1 = fmaf(h.w, w.w, a1);
        } else {
            a0 = fmaf(h.x, w.x, a0); a0 = fmaf(h.y, w.y, a0);
            a0 = fmaf(h.z, w.z, a0); a0 = fmaf(h.w, w.w, a0);
        }
    }
    return a0 + a1;
}

// dot of 20: h from LDS, w resident in registers (static indices after unroll).
__device__ __forceinline__ float dot20r(const float* hp, const float* wr) {
    float a0 = 0.f, a1 = 0.f;
#pragma unroll
    for (int q = 0; q < 5; ++q) {
        float4 h = ((const float4*)hp)[q];
        if (q & 1) {
            a1 = fmaf(h.x, wr[4*q+0], a1); a1 = fmaf(h.y, wr[4*q+1], a1);
            a1 = fmaf(h.z, wr[4*q+2], a1); a1 = fmaf(h.w, wr[4*q+3], a1);
        } else {
            a0 = fmaf(h.x, wr[4*q+0], a0); a0 = fmaf(h.y, wr[4*q+1], a0);
            a0 = fmaf(h.z, wr[4*q+2], a0); a0 = fmaf(h.w, wr[4*q+3], a0);
        }
    }
    return a0 + a1;
}

__global__ __launch_bounds__(THREADS, 4) void rnn_fused(
    const float* __restrict__ x,
    const float* __restrict__ w_ih0, const float* __restrict__ w_hh0,
    const float* __restrict__ b_ih0, const float* __restrict__ b_hh0,
    const float* __restrict__ w_ih1, const float* __restrict__ w_hh1,
    const float* __restrict__ b_ih1, const float* __restrict__ b_hh1,
    const float* __restrict__ w_ih2, const float* __restrict__ w_hh2,
    const float* __restrict__ b_ih2, const float* __restrict__ b_hh2,
    const float* __restrict__ fc_w,  const float* __restrict__ fc_b,
    float* __restrict__ out)
{
    __shared__ __align__(16) float h0buf[2][NB][HP];
    __shared__ __align__(16) float h1buf[2][NB][HP];
    __shared__ __align__(16) float h2buf[2][NB][HP];
    __shared__ __align__(16) float whh0s[H][H];   // LDS-resident weight (broadcast reads)
    __shared__ __align__(16) float wih2s[H][H];   // LDS-resident weight

    const int tid = threadIdx.x;
    const int b   = tid / H;
    const int j   = tid % H;
    const int gb  = blockIdx.x * NB + b;
    const size_t xbase = (size_t)gb * T_LEN;

    // Stage the two LDS-resident weight matrices.
    for (int i = tid; i < H * H; i += THREADS) {
        whh0s[i / H][i % H] = w_hh0[i];
        wih2s[i / H][i % H] = w_ih2[i];
    }
    // Zero both halves of all h double-buffers (h(-1)=0 initial states).
    for (int i = tid; i < 2 * NB * HP; i += THREADS) {
        (&h0buf[0][0][0])[i] = 0.f;
        (&h1buf[0][0][0])[i] = 0.f;
        (&h2buf[0][0][0])[i] = 0.f;
    }

    // Register-resident weight rows (row j).
    float wih1r[H], whh1r[H], whh2r[H];
#pragma unroll
    for (int k = 0; k < H; ++k) {
        wih1r[k] = w_ih1[j * H + k];
        whh1r[k] = w_hh1[j * H + k];
        whh2r[k] = w_hh2[j * H + k];
    }
    const float wih0j = w_ih0[j];
    const float bias0 = b_ih0[j] + b_hh0[j];
    const float bias1 = b_ih1[j] + b_hh1[j];
    const float bias2 = b_ih2[j] + b_hh2[j];

    __syncthreads();

    // Diagonal pipeline: at tick s we produce h0(s), h1(s-1), h2(s-2).
    // All inputs come from the previous tick's buffer -> ONE barrier per tick.

    // ---- tick s=0: layer0 only. h0(0) = tanh(x0*w + b)   (h0(-1)=0)
    {
        float a0 = fmaf(x[xbase + 0], wih0j, bias0);
        h0buf[0][b][j] = fast_tanh(a0);
        __syncthreads();
    }
    // ---- tick s=1: layer0 + layer1.
    {
        const float* h0p = &h0buf[0][b][0];
        float a0 = dot20(h0p, &whh0s[j][0]);
        a0 += fmaf(x[xbase + 1], wih0j, bias0);
        float a1 = dot20r(h0p, wih1r) + bias1;          // h1(0): h1(-1)=0
        h0buf[1][b][j] = fast_tanh(a0);
        h1buf[1][b][j] = fast_tanh(a1);
        __syncthreads();
    }
    // ---- main loop: ticks s=2..511, all three layers active.
    for (int s = 2; s < T_LEN; ++s) {
        const int cur = s & 1, prv = cur ^ 1;
        const float xt = x[xbase + s];
        const float* h0p = &h0buf[prv][b][0];
        const float* h1p = &h1buf[prv][b][0];
        const float* h2p = &h2buf[prv][b][0];

        // layer0: h0(s)
        float a0 = dot20(h0p, &whh0s[j][0]);
        // layer1: h1(s-1) = tanh(h0(s-1)·wih1 + h1(s-2)·whh1 + bias1)
        float a1 = dot20r(h0p, wih1r);
        a1 += dot20r(h1p, whh1r) + bias1;
        // layer2: h2(s-2) = tanh(h1(s-2)·wih2 + h2(s-3)·whh2 + bias2)
        float a2 = dot20(h1p, &wih2s[j][0]);
        a2 += dot20r(h2p, whh2r) + bias2;

        a0 += fmaf(xt, wih0j, bias0);   // late use of global load

        h0buf[cur][b][j] = fast_tanh(a0);
        h1buf[cur][b][j] = fast_tanh(a1);
        h2buf[cur][b][j] = fast_tanh(a2);
        __syncthreads();
    }
    // ---- tick s=512: layer1 + layer2. (cur=0, prv=1)
    {
        const float* h0p = &h0buf[1][b][0];
        const float* h1p = &h1buf[1][b][0];
        const float* h2p = &h2buf[1][b][0];
        float a1 = dot20r(h0p, wih1r);
        a1 += dot20r(h1p, whh1r) + bias1;               // h1(511)
        float a2 = dot20(h1p, &wih2s[j][0]);
        a2 += dot20r(h2p, whh2r) + bias2;               // h2(510)
        h1buf[0][b][j] = fast_tanh(a1);
        h2buf[0][b][j] = fast_tanh(a2);
        __syncthreads();
    }
    // ---- tick s=513: layer2 only. (cur=1, prv=0)
    {
        const float* h1p = &h1buf[0][b][0];
        const float* h2p = &h2buf[0][b][0];
        float a2 = dot20(h1p, &wih2s[j][0]);
        a2 += dot20r(h2p, whh2r) + bias2;               // h2(511)
        h2buf[1][b][j] = fast_tanh(a2);
        __syncthreads();
    }

    // Final FC: out[b] = fc_w · h2(511) + fc_b
    if (j == 0) {
        float acc = fc_b[0];
        const float* hp = &h2buf[1][b][0];
#pragma unroll
        for (int k = 0; k < H; ++k)
            acc = fmaf(hp[k], fc_w[k], acc);
        out[gb] = acc;
    }
}

extern "C" void kernel_launch(void* const* d_in, const int* in_sizes, int n_in,
                              void* d_out, int out_size, void* d_ws, size_t ws_size,
                              hipStream_t stream) {
    const float* x     = (const float*)d_in[0];
    const float* w_ih0 = (const float*)d_in[1];
    const float* w_hh0 = (const float*)d_in[2];
    const float* b_ih0 = (const float*)d_in[3];
    const float* b_hh0 = (const float*)d_in[4];
    const float* w_ih1 = (const float*)d_in[5];
    const float* w_hh1 = (const float*)d_in[6];
    const float* b_ih1 = (const float*)d_in[7];
    const float* b_hh1 = (const float*)d_in[8];
    const float* w_ih2 = (const float*)d_in[9];
    const float* w_hh2 = (const float*)d_in[10];
    const float* b_ih2 = (const float*)d_in[11];
    const float* b_hh2 = (const float*)d_in[12];
    const float* fc_w  = (const float*)d_in[13];
    const float* fc_b  = (const float*)d_in[14];
    float* out = (float*)d_out;

    rnn_fused<<<B_TOTAL / NB, THREADS, 0, stream>>>(
        x, w_ih0, w_hh0, b_ih0, b_hh0,
        w_ih1, w_hh1, b_ih1, b_hh1,
        w_ih2, w_hh2, b_ih2, b_hh2,
        fc_w, fc_b, out);
}

// Round 3
// 319.127 us; speedup vs baseline: 3.5775x; 3.5775x over previous
//
#include <hip/hip_runtime.h>
#include <hip/hip_bf16.h>

// B=8192, T=512, IN=1, H=20, OUT=1
#define B_TOTAL 8192
#define T_LEN   512
#define H       20
#define NBW     3      // real batches per wave (3*20=60 lanes; lanes 60-63 are dummies -> row 3)
#define XSTR    520    // xs row stride (520%32==8 -> banks 8*bb+s, conflict-free)

__device__ __forceinline__ float fast_tanh(float x) {
    float e = __expf(2.0f * x);
    return 1.0f - 2.0f * __builtin_amdgcn_rcpf(e + 1.0f);
}

// Load 20 floats (5x float4) from LDS into named regs.
#define RD5(dst, base) \
    float4 dst##a = ((const float4*)(base))[0]; \
    float4 dst##b = ((const float4*)(base))[1]; \
    float4 dst##c = ((const float4*)(base))[2]; \
    float4 dst##d = ((const float4*)(base))[3]; \
    float4 dst##e = ((const float4*)(base))[4];

// acc += h . w  with 2 accumulator chains; w is a local array, literal indices only.
#define DOT20(accA, accB, hv, wr) \
    accA = fmaf(hv##a.x, wr[0],  accA); accB = fmaf(hv##a.y, wr[1],  accB); \
    accA = fmaf(hv##a.z, wr[2],  accA); accB = fmaf(hv##a.w, wr[3],  accB); \
    accA = fmaf(hv##b.x, wr[4],  accA); accB = fmaf(hv##b.y, wr[5],  accB); \
    accA = fmaf(hv##b.z, wr[6],  accA); accB = fmaf(hv##b.w, wr[7],  accB); \
    accA = fmaf(hv##c.x, wr[8],  accA); accB = fmaf(hv##c.y, wr[9],  accB); \
    accA = fmaf(hv##c.z, wr[10], accA); accB = fmaf(hv##c.w, wr[11], accB); \
    accA = fmaf(hv##d.x, wr[12], accA); accB = fmaf(hv##d.y, wr[13], accB); \
    accA = fmaf(hv##d.z, wr[14], accA); accB = fmaf(hv##d.w, wr[15], accB); \
    accA = fmaf(hv##e.x, wr[16], accA); accB = fmaf(hv##e.y, wr[17], accB); \
    accA = fmaf(hv##e.z, wr[18], accA); accB = fmaf(hv##e.w, wr[19], accB);

// One diagonal-pipeline tick: produce h0(s) [DO0], h1(s-1) [DO1], h2(s-2) [DO2].
// Reads (prev state) are issued before writes; single wave => DS in-order, no barrier.
#define TICK(sidx, DO0, DO1, DO2) { \
    float t0 = 0.f, t1 = 0.f, t2 = 0.f; \
    if (DO0 || DO1) { \
        RD5(h0v, &h0s[bb][0]) \
        if (DO0) { \
            float a0A = fmaf(xs[bb][(sidx)], wih0j, bias0), a0B = 0.f; \
            DOT20(a0A, a0B, h0v, whh0r) \
            t0 = fast_tanh(a0A + a0B); \
        } \
        if (DO1) { \
            float a1A = bias1, a1B = 0.f; \
            DOT20(a1A, a1B, h0v, wih1r) \
            RD5(h1vA, &h1s[bb][0]) \
            float a1C = 0.f, a1D = 0.f; \
            DOT20(a1C, a1D, h1vA, whh1r) \
            t1 = fast_tanh(a1A + a1B + a1C + a1D); \
            if (DO2) { \
                float a2A = bias2, a2B = 0.f; \
                DOT20(a2A, a2B, h1vA, wih2r) \
                RD5(h2v, &h2s[bb][0]) \
                float a2C = 0.f, a2D = 0.f; \
                DOT20(a2C, a2D, h2v, whh2r) \
                t2 = fast_tanh(a2A + a2B + a2C + a2D); \
            } \
        } else if (DO2) { \
            RD5(h1vB, &h1s[bb][0]) \
            float a2A = bias2, a2B = 0.f; \
            DOT20(a2A, a2B, h1vB, wih2r) \
            RD5(h2v, &h2s[bb][0]) \
            float a2C = 0.f, a2D = 0.f; \
            DOT20(a2C, a2D, h2v, whh2r) \
            t2 = fast_tanh(a2A + a2B + a2C + a2D); \
        } \
    } else if (DO2) { \
        RD5(h1vC, &h1s[bb][0]) \
        float a2A = bias2, a2B = 0.f; \
        DOT20(a2A, a2B, h1vC, wih2r) \
        RD5(h2v, &h2s[bb][0]) \
        float a2C = 0.f, a2D = 0.f; \
        DOT20(a2C, a2D, h2v, whh2r) \
        t2 = fast_tanh(a2A + a2B + a2C + a2D); \
    } \
    if (DO0) h0s[bb][j] = t0; \
    if (DO1) h1s[bb][j] = t1; \
    if (DO2) h2s[bb][j] = t2; \
}

__global__ __launch_bounds__(64, 3) void rnn_wave(
    const float* __restrict__ x,
    const float* __restrict__ w_ih0, const float* __restrict__ w_hh0,
    const float* __restrict__ b_ih0, const float* __restrict__ b_hh0,
    const float* __restrict__ w_ih1, const float* __restrict__ w_hh1,
    const float* __restrict__ b_ih1, const float* __restrict__ b_hh1,
    const float* __restrict__ w_ih2, const float* __restrict__ w_hh2,
    const float* __restrict__ b_ih2, const float* __restrict__ b_hh2,
    const float* __restrict__ fc_w,  const float* __restrict__ fc_b,
    float* __restrict__ out)
{
    __shared__ __align__(16) float xs[4][XSTR];   // row 3 = dummy-lane target
    __shared__ __align__(16) float h0s[4][H];     // stride 20: read chunks + writes are
    __shared__ __align__(16) float h1s[4][H];     //   conflict-free / 2-way (verified)
    __shared__ __align__(16) float h2s[4][H];

    const int lane = threadIdx.x;      // block == one wave
    const int bb   = lane / H;         // 0..3 (3 = dummy lanes 60-63)
    const int j    = lane - bb * H;    // 0..19 (dummy: 0..3)
    const int gb   = blockIdx.x * NBW + bb;

    // ---- one-time: stage x rows (coalesced float4), zero h state ----
    {
        const int gb0 = blockIdx.x * NBW;
        #pragma unroll
        for (int it = 0; it < 6; ++it) {
            int fidx = (it * 64 + lane) * 4;        // 0..1532
            int row  = fidx >> 9;
            int col  = fidx & 511;
            int grow = gb0 + row;
            if (grow > B_TOTAL - 1) grow = B_TOTAL - 1;
            float4 v = *(const float4*)(x + (size_t)grow * T_LEN + col);
            *(float4*)&xs[row][col] = v;
        }
        for (int i = lane; i < 4 * H; i += 64) {
            (&h0s[0][0])[i] = 0.f;
            (&h1s[0][0])[i] = 0.f;
            (&h2s[0][0])[i] = 0.f;
        }
        // dummy-lane x row: fill with finite values (row 3 never staged above if NBW<4)
        for (int i = lane; i < XSTR; i += 64) xs[3][i] = 0.f;
    }

    // ---- per-lane weights (row j of each matrix) in registers ----
    float whh0r[H], wih1r[H], whh1r[H], wih2r[H], whh2r[H];
    #pragma unroll
    for (int k = 0; k < H; ++k) {
        whh0r[k] = w_hh0[j * H + k];
        wih1r[k] = w_ih1[j * H + k];
        whh1r[k] = w_hh1[j * H + k];
        wih2r[k] = w_ih2[j * H + k];
        whh2r[k] = w_hh2[j * H + k];
    }
    const float wih0j = w_ih0[j];
    const float bias0 = b_ih0[j] + b_hh0[j];
    const float bias1 = b_ih1[j] + b_hh1[j];
    const float bias2 = b_ih2[j] + b_hh2[j];

    // ---- diagonal pipeline, wave-synchronous (no barriers at all) ----
    TICK(0, 1, 0, 0)
    TICK(1, 1, 1, 0)
    for (int s = 2; s < T_LEN; ++s) {
        TICK(s, 1, 1, 1)
    }
    TICK(512, 0, 1, 1)   // h1(511), h2(510)
    TICK(513, 0, 0, 1)   // h2(511)

    // ---- FC epilogue ----
    if (j == 0 && bb < NBW && gb < B_TOTAL) {
        float acc = fc_b[0];
        #pragma unroll
        for (int k = 0; k < H; ++k)
            acc = fmaf(h2s[bb][k], fc_w[k], acc);
        out[gb] = acc;
    }
}

extern "C" void kernel_launch(void* const* d_in, const int* in_sizes, int n_in,
                              void* d_out, int out_size, void* d_ws, size_t ws_size,
                              hipStream_t stream) {
    const float* x     = (const float*)d_in[0];
    const float* w_ih0 = (const float*)d_in[1];
    const float* w_hh0 = (const float*)d_in[2];
    const float* b_ih0 = (const float*)d_in[3];
    const float* b_hh0 = (const float*)d_in[4];
    const float* w_ih1 = (const float*)d_in[5];
    const float* w_hh1 = (const float*)d_in[6];
    const float* b_ih1 = (const float*)d_in[7];
    const float* b_hh1 = (const float*)d_in[8];
    const float* w_ih2 = (const float*)d_in[9];
    const float* w_hh2 = (const float*)d_in[10];
    const float* b_ih2 = (const float*)d_in[11];
    const float* b_hh2 = (const float*)d_in[12];
    const float* fc_w  = (const float*)d_in[13];
    const float* fc_b  = (const float*)d_in[14];
    float* out = (float*)d_out;

    const int nblocks = (B_TOTAL + NBW - 1) / NBW;   // 2731
    rnn_wave<<<nblocks, 64, 0, stream>>>(
        x, w_ih0, w_hh0, b_ih0, b_hh0,
        w_ih1, w_hh1, b_ih1, b_hh1,
        w_ih2, w_hh2, b_ih2, b_hh2,
        fc_w, fc_b, out);
}